// Round 5
// baseline (207.294 us; speedup 1.0000x reference)
//
#include <hip/hip_runtime.h>
#include <math.h>

// PPO loss with GAE.  B=4096 rows, T=2048 steps, fp32 inputs.
// Inputs: 0 rewards(B,T) 1 values(B,T+1) 2 ref_probs(UNUSED) 3 old_probs(B,T)
//         4 curr_probs(B,T) 5 masks(B,T)
// Output: 4 floats: total, ppo, 0.5*value_loss, 0.01*entropy_loss
//
// R10: latency theory falsified (R9 forced-MLP: occupancy 40->57%, only -2us;
// 3 schedules all hit the same ~2.8 TB/s demand wall while fillBuffer hits
// 6.6 TB/s in the same capture). Common factor: every load had 32B lane
// stride (thread owns 8 contiguous elems). This round: unit-stride everything.
//  - gae: chunk 4 elems/thread, 512 thr/row. rewards/masks 1x float4,
//    values 2x float4 aligned window (ofs=row&3 uniform) -- all lane-stride
//    16B. Chunk-4 scan -> same verified 64-lane butterfly -> 8-wave compose.
//  - ppo: two groups of 4 elems at [blk*2048+tid*4] and +1024 -> 6 loads all
//    unit-stride.
// Tell: gae ~18-22us & ppo ~14-17us if stride was the wall; unchanged = not.

#define GAMMA     0.99f
#define LAM       0.95f
#define CLIP_LO   0.8f
#define CLIP_HI   1.2f
#define EPSF      1e-9f

constexpr int BB = 4096;
constexpr int TT = 2048;
constexpr long long NN = (long long)BB * TT;   // 8388608
constexpr int GAE_BLOCKS = BB;                 // 1 row per block, 512 threads
constexpr int PPO_BLOCKS = 4096;               // 8 elems/thread, 256 threads

// ws layout:
//  [0,32)          stats: float mean, float inv_std_eps, double sum_adv2
//  [64, +32K)      gae partials: 4096 x float2
//  [32832, +32K)   ppo partials: 4096 x float2
//  [65600, +16.8M) adv in bf16 (uint4-aligned; 65600 % 16 == 0)
struct Stats { float mean; float inv; double sum2; };
static constexpr size_t GAE_PART_OFF = 64;
static constexpr size_t PPO_PART_OFF = GAE_PART_OFF + GAE_BLOCKS * sizeof(float2); // 32832
static constexpr size_t ADV_OFF      = PPO_PART_OFF + PPO_BLOCKS * sizeof(float2); // 65600

__device__ __forceinline__ unsigned bf16_rne(float x) {
    unsigned u = __float_as_uint(x);
    u += 0x7FFFu + ((u >> 16) & 1u);
    return u >> 16;
}

// ---------------------------------------------------------------- K1: GAE scan
// 512 threads = 8 waves per row; thread owns elements [4*tid, 4*tid+4).
__global__ __launch_bounds__(512, 4) void gae_kernel(
    const float* __restrict__ rewards,
    const float* __restrict__ values,
    const float* __restrict__ masks,
    uint4* __restrict__ advb,          // bf16: 4 elems per uint2
    float2* __restrict__ partials)
{
    const int tid  = threadIdx.x;      // 0..511
    const int lane = tid & 63;
    const int wave = tid >> 6;         // 0..7
    const int e0   = tid * 4;
    const int r    = blockIdx.x;

    __shared__ float2 wT[8];
    __shared__ float  wr1[8], wr2[8];

    // rewards/masks rows: stride 2048 floats -> float4 aligned, lane stride 16B.
    const float* rp = rewards + (size_t)r * TT;
    const float* mp = masks   + (size_t)r * TT;
    // values row: stride 2049. Aligned float4 window: element e of the row is
    // word vw+e; with base (vw & ~3), thread needs words ofs+e0 .. ofs+e0+4
    // (ofs = vw & 3, wave-uniform) which lie in v4[tid] and v4[tid+1].
    // OOB: worst case r=4095 (ofs=3), tid=511: v4[512] covers words
    // vw-3+2048 .. vw-3+2051 = global words 8392700..8392703; values has
    // 4096*2049 = 8392704 words. Exactly in bounds.
    const size_t vw  = (size_t)r * (TT + 1);
    const int    ofs = (int)(vw & 3);
    const float4* v4 = (const float4*)(values + (vw & ~(size_t)3));

    float4 R  = *(const float4*)(rp + e0);
    float4 M  = *(const float4*)(mp + e0);
    float4 V0 = v4[tid];
    float4 V1 = v4[tid + 1];

    // ---- extract the 5 needed values (wave-uniform branch, static indices)
    float ff[8] = {V0.x, V0.y, V0.z, V0.w, V1.x, V1.y, V1.z, V1.w};
    float vv[5];
    if (ofs == 0) {
#pragma unroll
        for (int j = 0; j < 5; ++j) vv[j] = ff[j];
    } else if (ofs == 1) {
#pragma unroll
        for (int j = 0; j < 5; ++j) vv[j] = ff[j + 1];
    } else if (ofs == 2) {
#pragma unroll
        for (int j = 0; j < 5; ++j) vv[j] = ff[j + 2];
    } else {
#pragma unroll
        for (int j = 0; j < 5; ++j) vv[j] = ff[j + 3];
    }

    float rr[4] = {R.x, R.y, R.z, R.w};
    float mm[4] = {M.x, M.y, M.z, M.w};

    // ---- chunk-local reverse affine scan over 4 elems
    float la[4], S[4];
    {
        float d[4], c[4];
#pragma unroll
        for (int j = 0; j < 4; ++j) {
            d[j] = rr[j] + GAMMA * vv[j + 1] * mm[j] - vv[j];
            c[j] = (GAMMA * LAM) * mm[j];
        }
        la[3] = d[3]; S[3] = c[3];
#pragma unroll
        for (int j = 2; j >= 0; --j) {
            la[j] = d[j] + c[j] * la[j + 1];
            S[j]  = c[j] * S[j + 1];
        }
    }

    // ---- wave-level suffix scan of affine fns (verified butterfly)
    float A = S[0], Bv = la[0];
#pragma unroll
    for (int d2 = 1; d2 < 64; d2 <<= 1) {
        float A2 = __shfl_down(A, d2, 64), B2 = __shfl_down(Bv, d2, 64);
        if (lane + d2 < 64) { Bv = Bv + A * B2; A = A * A2; }
    }
    // lane 0 now holds the whole wave's composed affine fn
    if (lane == 0) wT[wave] = make_float2(A, Bv);
    __syncthreads();
    // carry entering this wave = compose of waves wave+1..7 applied to 0
    float C = 0.f;
    for (int ww = 7; ww > wave; --ww) C = wT[ww].y + wT[ww].x * C;
    float A1 = __shfl_down(A, 1, 64), B1 = __shfl_down(Bv, 1, 64);
    float car = (lane < 63) ? (B1 + A1 * C) : C;

    // ---- final adv, fp32 sums, bf16 pack + store (uint2, unit stride)
    float s1 = 0.f, s2 = 0.f;
    unsigned hh[4];
#pragma unroll
    for (int j = 0; j < 4; ++j) {
        float a = la[j] + S[j] * car;
        s1 += a; s2 += a * a;
        hh[j] = bf16_rne(a);
    }
    uint2 pk = {hh[0] | (hh[1] << 16), hh[2] | (hh[3] << 16)};
    ((uint2*)advb)[(size_t)r * 512 + tid] = pk;

    // ---- block reduce (8 waves) -> one float2 per block
#pragma unroll
    for (int off = 32; off > 0; off >>= 1) {
        s1 += __shfl_down(s1, off, 64);
        s2 += __shfl_down(s2, off, 64);
    }
    if (lane == 0) { wr1[wave] = s1; wr2[wave] = s2; }
    __syncthreads();
    if (tid == 0) {
        float t1 = 0.f, t2 = 0.f;
#pragma unroll
        for (int w = 0; w < 8; ++w) { t1 += wr1[w]; t2 += wr2[w]; }
        partials[blockIdx.x] = make_float2(t1, t2);
    }
}

// ------------------------------------- K2: reduce gae partials -> mean, inv_std
__global__ __launch_bounds__(256) void finalize_stats(
    const float2* __restrict__ gp, Stats* __restrict__ stats)
{
    const int tid = threadIdx.x;
    __shared__ double l1[256], l2[256];
    double s1 = 0.0, s2 = 0.0;
    for (int i = tid; i < GAE_BLOCKS; i += 256) {
        float2 p = gp[i];
        s1 += (double)p.x;
        s2 += (double)p.y;
    }
    l1[tid] = s1; l2[tid] = s2;
    __syncthreads();
    for (int st = 128; st > 0; st >>= 1) {
        if (tid < st) { l1[tid] += l1[tid + st]; l2[tid] += l2[tid + st]; }
        __syncthreads();
    }
    if (tid == 0) {
        double S1 = l1[0], S2 = l2[0];
        double mean = S1 / (double)NN;
        double var  = (S2 - S1 * S1 / (double)NN) / (double)(NN - 1); // ddof=1
        stats->mean = (float)mean;
        stats->inv  = (float)(1.0 / (sqrt(var) + 1e-9));
        stats->sum2 = S2;
    }
}

// ------------------------------------------------- K3: ppo surrogate + entropy
// Thread handles two groups of 4 elems: [blk*2048 + tid*4) and +1024.
// All 6 loads unit-stride across the wave.
__global__ __launch_bounds__(256, 8) void ppo_kernel(
    const float* __restrict__ adv_bf16,   // raw bf16 pairs, 4 elems per uint2
    const float* __restrict__ oldp,
    const float* __restrict__ currp,
    const Stats* __restrict__ stats,
    float2* __restrict__ partials)
{
    const float mean = stats->mean;
    const float inv  = stats->inv;
    const int tid = threadIdx.x;
    const int i0  = blockIdx.x * 512 + tid;     // float4 / uint2 index, group 0
    const int i1  = i0 + 256;                   // group 1

    const uint2*  a2 = (const uint2*)adv_bf16;
    const float4* o4 = (const float4*)oldp;
    const float4* c4 = (const float4*)currp;

    uint2  A0 = a2[i0], A1 = a2[i1];
    float4 O0 = o4[i0], O1 = o4[i1];
    float4 C0 = c4[i0], C1 = c4[i1];

    float av[8] = {__uint_as_float(A0.x << 16), __uint_as_float(A0.x & 0xFFFF0000u),
                   __uint_as_float(A0.y << 16), __uint_as_float(A0.y & 0xFFFF0000u),
                   __uint_as_float(A1.x << 16), __uint_as_float(A1.x & 0xFFFF0000u),
                   __uint_as_float(A1.y << 16), __uint_as_float(A1.y & 0xFFFF0000u)};
    float ov[8] = {O0.x, O0.y, O0.z, O0.w, O1.x, O1.y, O1.z, O1.w};
    float cv[8] = {C0.x, C0.y, C0.z, C0.w, C1.x, C1.y, C1.z, C1.w};

    float sm = 0.f, se = 0.f;
#pragma unroll
    for (int j = 0; j < 8; ++j) {
        float an    = (av[j] - mean) * inv;
        float ratio = cv[j] * __builtin_amdgcn_rcpf(ov[j] + EPSF);
        float rc    = fminf(fmaxf(ratio, CLIP_LO), CLIP_HI);
        sm += fminf(ratio * an, rc * an);
        se += cv[j] * __logf(cv[j] + EPSF);
    }

#pragma unroll
    for (int off = 32; off > 0; off >>= 1) {
        sm += __shfl_down(sm, off, 64);
        se += __shfl_down(se, off, 64);
    }
    __shared__ float w1[4], w2[4];
    const int wave = tid >> 6, lane = tid & 63;
    if (lane == 0) { w1[wave] = sm; w2[wave] = se; }
    __syncthreads();
    if (tid == 0) {
        float2 p = {w1[0] + w1[1] + w1[2] + w1[3],
                    w2[0] + w2[1] + w2[2] + w2[3]};
        partials[blockIdx.x] = p;
    }
}

// --------------------------------- K4: reduce ppo partials -> 4 output scalars
__global__ __launch_bounds__(256) void finalize_out(
    const float2* __restrict__ pp,
    const Stats* __restrict__ stats,
    float* __restrict__ out)
{
    const int tid = threadIdx.x;
    __shared__ double l1[256], l2[256];
    double s1 = 0.0, s2 = 0.0;
    for (int i = tid; i < PPO_BLOCKS; i += 256) {
        float2 p = pp[i];
        s1 += (double)p.x;
        s2 += (double)p.y;
    }
    l1[tid] = s1; l2[tid] = s2;
    __syncthreads();
    for (int st = 128; st > 0; st >>= 1) {
        if (tid < st) { l1[tid] += l1[tid + st]; l2[tid] += l2[tid + st]; }
        __syncthreads();
    }
    if (tid == 0) {
        double invN = 1.0 / (double)NN;
        double vl   = 0.5  * (stats->sum2 * invN);   // 0.5 * mean(raw_adv^2)
        double ppo  = -(l1[0] * invN);
        double ent  = -0.01 * (l2[0] * invN);
        out[0] = (float)(ppo + vl + ent);
        out[1] = (float)ppo;
        out[2] = (float)vl;
        out[3] = (float)ent;
    }
}

extern "C" void kernel_launch(void* const* d_in, const int* in_sizes, int n_in,
                              void* d_out, int out_size, void* d_ws, size_t ws_size,
                              hipStream_t stream) {
    const float* rewards = (const float*)d_in[0];
    const float* values  = (const float*)d_in[1];
    // d_in[2] = ref_probs: unused by the reference
    const float* oldp    = (const float*)d_in[3];
    const float* currp   = (const float*)d_in[4];
    const float* masks   = (const float*)d_in[5];

    Stats*  stats = (Stats*)d_ws;
    float2* gaep  = (float2*)((char*)d_ws + GAE_PART_OFF);
    float2* ppop  = (float2*)((char*)d_ws + PPO_PART_OFF);
    uint4*  advb  = (uint4*)((char*)d_ws + ADV_OFF);
    float*  out   = (float*)d_out;

    gae_kernel<<<GAE_BLOCKS, 512, 0, stream>>>(rewards, values, masks, advb, gaep);
    finalize_stats<<<1, 256, 0, stream>>>(gaep, stats);
    ppo_kernel<<<PPO_BLOCKS, 256, 0, stream>>>((const float*)advb, oldp, currp, stats, ppop);
    finalize_out<<<1, 256, 0, stream>>>(ppop, stats, out);
}